// Round 7
// baseline (31436.105 us; speedup 1.0000x reference)
//
#include <hip/hip_runtime.h>
#include <cstdint>
#include <cstddef>

#define BB 32
#define SS 512
#define HH 512
#define NBD 64      // blocks per direction
#define JPB 8       // j columns per block
#define WR 32       // W rows per block (4 gates * JPB)
#define WST 520     // Whh LDS row stride (1040 B, breaks bank alignment)

typedef short v8s __attribute__((ext_vector_type(8)));
typedef float v4f __attribute__((ext_vector_type(4)));

static __device__ __forceinline__ float b2f(unsigned short u) {
    union { unsigned int i; float f; } v; v.i = ((unsigned int)u) << 16; return v.f;
}
static __device__ __forceinline__ unsigned short f2b(float f) {
    union { float f; unsigned int i; } v; v.f = f;
    unsigned int u = v.i;
    return (unsigned short)((u + 0x7fffu + ((u >> 16) & 1u)) >> 16);  // RNE
}
static __device__ __forceinline__ void split1(float f, short& hi, short& lo) {
    const unsigned short h = f2b(f);
    hi = (short)h;
    lo = (short)f2b(f - b2f(h));   // exact residual, then RNE
}
static __device__ __forceinline__ void split8(const float* __restrict__ p, v8s& hi, v8s& lo) {
    #pragma unroll
    for (int e = 0; e < 8; ++e) { short h, l; split1(p[e], h, l); hi[e] = h; lo[e] = l; }
}

#define MFMA(a, b, c) __builtin_amdgcn_mfma_f32_16x16x32_bf16((a), (b), (c), 0, 0, 0)

// One bidirectional layer; persistent blocks, spin-barrier per timestep.
// blockIdx: [0,64) forward, [64,128) backward j-blocks.
// *** Barrier counters are PER-DIRECTION (ctr[dir*S + st], wait < 64). ***
// r5/r6 bug: shared ctr across dirs opened the barrier after any 64 of 128
// mixed publishes -> stale/zero h reads -> 4e-2 error. Fixed here.
// L0=true : x = f32 input; yout = bf16 packed [B,S,2H] (layer-1 input);
//           h-recurrence via f32 parity double-buffer hrec (agent atomics).
// L0=false: x = bf16 y0;   yout = f32 d_out [B,S,2H]; h-recurrence reads f32
//           h history straight from yout (each t-slot written exactly once).
template<int DIN, bool L0>
__global__ __launch_bounds__(256, 1)
void lstm_layer(const void*  __restrict__ xin_,
                const float* __restrict__ Wih_f,  // [4H, DIN] f32
                const float* __restrict__ Whh_f,  // [4H, H]  f32
                const float* __restrict__ b_f,    // [4H]     f32
                const float* __restrict__ Wih_b,
                const float* __restrict__ Whh_b,
                const float* __restrict__ b_b,
                void*  __restrict__ yout_,
                float* __restrict__ hrec,          // [2dir][2par][B][H] f32 (L0 only)
                unsigned int* __restrict__ ctr,    // [2dir][S], zeroed each call
                float* __restrict__ hn,            // [2][B][H] f32 (layer 1)
                float* __restrict__ cn)            // [2][B][H] f32 (layer 1)
{
    constexpr int NKX = DIN / 32;
    constexpr int NKH = HH / 32;

    extern __shared__ char smem[];
    unsigned short* WhhHi = (unsigned short*)smem;          // [32][WST]
    unsigned short* WhhLo = WhhHi + WR * WST;               // [32][WST]
    float* gatesl = (float*)(smem + 2 * WR * WST * 2);      // [32][36]
    float* biasl  = gatesl + 32 * 36;

    const int tid   = threadIdx.x;
    const int dir   = blockIdx.x >> 6;
    const int jb    = blockIdx.x & 63;
    const int jbase = jb * JPB;

    const float* Wih = dir ? Wih_b : Wih_f;
    const float* Whh = dir ? Whh_b : Whh_f;
    const float* bv  = dir ? b_b  : b_f;

    // ---- stage Whh slice split hi/lo into LDS ----
    {
        const int r  = tid >> 3;
        const int c0 = (tid & 7) * 64;
        const int R  = (r >> 3) * HH + jbase + (r & 7);   // gate*512 + j
        const float* src = Whh + (size_t)R * HH + c0;
        #pragma unroll
        for (int c = 0; c < 64; c += 8) {
            v8s hi, lo; split8(src + c, hi, lo);
            *(v8s*)(WhhHi + r * WST + c0 + c) = hi;
            *(v8s*)(WhhLo + r * WST + c0 + c) = lo;
        }
    }
    if (tid < WR) biasl[tid] = bv[(tid >> 3) * HH + jbase + (tid & 7)];

    const int lane = tid & 63;
    const int wv   = tid >> 6;
    const int mi   = wv & 1;         // M-frag (batch half)
    const int ni   = wv >> 1;        // N-frag (gate-row half)
    const int g    = lane >> 4;      // k-group
    const int rA   = lane & 15;

    const int brow = mi * 16 + rA;   // batch row (A-frag)
    const int nrow = ni * 16 + rA;   // local gate-row (B-frag)
    const int Rn   = (nrow >> 3) * HH + jbase + (nrow & 7);

    // ---- Wih B-fragments split hi/lo into registers (static indexing) ----
    v8s wxh[NKX], wxl[NKX];
    {
        const float* src = Wih + (size_t)Rn * DIN + 8 * g;
        #pragma unroll
        for (int kt = 0; kt < NKX; ++kt) split8(src + kt * 32, wxh[kt], wxl[kt]);
    }
    __syncthreads();

    const float*          aXf = L0 ? (const float*)xin_ + (size_t)brow * SS * DIN + 8 * g : nullptr;
    const unsigned short* aXb = L0 ? nullptr : (const unsigned short*)xin_ + (size_t)brow * SS * DIN + 8 * g;
    const unsigned short* bHb = WhhHi + nrow * WST + 8 * g;
    const unsigned short* bLb = WhhLo + nrow * WST + 8 * g;

    unsigned int* cbase = ctr + dir * SS;   // *** per-direction barrier ***

    const int eb = tid >> 3;         // epilogue: batch row
    const int ej = tid & 7;          // epilogue: local col
    float creg = 0.f;

    for (int st = 0; st < SS; ++st) {
        const int t = dir ? (SS - 1 - st) : st;

        v4f acc0 = {0,0,0,0}, acc1 = {0,0,0,0}, acc2 = {0,0,0,0};
        v4f acc3 = {0,0,0,0}, acc4 = {0,0,0,0}, acc5 = {0,0,0,0};

        // ---- x-part (pre-barrier; hides load + split latency) ----
        if (L0) {
            const float* aX = aXf + (size_t)t * DIN;
            #pragma unroll
            for (int kt = 0; kt < NKX; kt += 2) {
                v8s ah0, al0, ah1, al1;
                split8(aX + kt * 32, ah0, al0);
                split8(aX + (kt + 1) * 32, ah1, al1);
                acc0 = MFMA(ah0, wxh[kt],     acc0);
                acc1 = MFMA(ah1, wxh[kt + 1], acc1);
                acc2 = MFMA(ah0, wxl[kt],     acc2);
                acc3 = MFMA(ah1, wxl[kt + 1], acc3);
                acc4 = MFMA(al0, wxh[kt],     acc4);
                acc5 = MFMA(al1, wxh[kt + 1], acc5);
            }
        } else {
            const unsigned short* aX = aXb + (size_t)t * DIN;
            #pragma unroll
            for (int kt = 0; kt < NKX; kt += 2) {
                v8s a0 = *(const v8s*)(aX + kt * 32);
                v8s a1 = *(const v8s*)(aX + (kt + 1) * 32);
                acc0 = MFMA(a0, wxh[kt],     acc0);
                acc1 = MFMA(a1, wxh[kt + 1], acc1);
                acc2 = MFMA(a0, wxl[kt],     acc2);
                acc3 = MFMA(a1, wxl[kt + 1], acc3);
            }
        }

        // ---- wait for h_{t_prev}; h-part (skipped at st==0: h_{-1}=0) ----
        if (st > 0) {
            if (tid == 0) {
                int guard = 0;
                while (__hip_atomic_load(&cbase[st - 1], __ATOMIC_ACQUIRE,
                                         __HIP_MEMORY_SCOPE_AGENT) < NBD) {
                    __builtin_amdgcn_s_sleep(1);
                    if (++guard > (1 << 26)) break;
                }
            }
            __syncthreads();
            __builtin_amdgcn_fence(__ATOMIC_ACQUIRE, "agent");

            const unsigned int* hb;
            if (L0) {
                hb = (const unsigned int*)hrec
                   + ((size_t)(dir * 2 + ((st - 1) & 1))) * BB * HH + brow * HH + 8 * g;
            } else {
                const int tp = dir ? t + 1 : t - 1;
                hb = (const unsigned int*)yout_
                   + (size_t)brow * SS * (2 * HH) + (size_t)tp * (2 * HH) + dir * HH + 8 * g;
            }
            #pragma unroll
            for (int kt = 0; kt < NKH; kt += 2) {
                float h0[8], h1[8];
                #pragma unroll
                for (int e = 0; e < 8; ++e) {
                    h0[e] = __uint_as_float(__hip_atomic_load(hb + kt * 32 + e,
                                __ATOMIC_RELAXED, __HIP_MEMORY_SCOPE_AGENT));
                    h1[e] = __uint_as_float(__hip_atomic_load(hb + (kt + 1) * 32 + e,
                                __ATOMIC_RELAXED, __HIP_MEMORY_SCOPE_AGENT));
                }
                v8s ah0, al0, ah1, al1;
                #pragma unroll
                for (int e = 0; e < 8; ++e) {
                    short h, l;
                    split1(h0[e], h, l); ah0[e] = h; al0[e] = l;
                    split1(h1[e], h, l); ah1[e] = h; al1[e] = l;
                }
                v8s bh0 = *(const v8s*)(bHb + kt * 32);
                v8s bl0 = *(const v8s*)(bLb + kt * 32);
                v8s bh1 = *(const v8s*)(bHb + (kt + 1) * 32);
                v8s bl1 = *(const v8s*)(bLb + (kt + 1) * 32);
                acc0 = MFMA(ah0, bh0, acc0);
                acc1 = MFMA(ah1, bh1, acc1);
                acc2 = MFMA(ah0, bl0, acc2);
                acc3 = MFMA(ah1, bl1, acc3);
                acc4 = MFMA(al0, bh0, acc4);
                acc5 = MFMA(al1, bh1, acc5);
            }
        }
        acc0 = ((acc0 + acc1) + (acc2 + acc3)) + (acc4 + acc5);

        // ---- exchange gate preacts via LDS (C/D m89, probe-confirmed r4) ----
        {
            const int gb = mi * 16 + 4 * g;
            const int gw = ni * 16 + rA;
            gatesl[(gb + 0) * 36 + gw] = acc0[0];
            gatesl[(gb + 1) * 36 + gw] = acc0[1];
            gatesl[(gb + 2) * 36 + gw] = acc0[2];
            gatesl[(gb + 3) * 36 + gw] = acc0[3];
        }
        __syncthreads();

        // ---- gates (torch order i,f,g,o) + state update ----
        {
            const float pi = gatesl[eb * 36 +      ej] + biasl[     ej];
            const float pf = gatesl[eb * 36 +  8 + ej] + biasl[ 8 + ej];
            const float pg = gatesl[eb * 36 + 16 + ej] + biasl[16 + ej];
            const float po = gatesl[eb * 36 + 24 + ej] + biasl[24 + ej];
            const float ig = 1.f / (1.f + __expf(-pi));
            const float fg = 1.f / (1.f + __expf(-pf));
            const float gg = tanhf(pg);
            const float og = 1.f / (1.f + __expf(-po));
            creg = fg * creg + ig * gg;
            const float h = og * tanhf(creg);

            if (L0) {
                // f32 h -> parity buffer (agent atomic: cross-XCD coherent point)
                unsigned int* hw = (unsigned int*)hrec
                                 + ((size_t)(dir * 2 + (st & 1))) * BB * HH + eb * HH + jbase + ej;
                __hip_atomic_store(hw, __float_as_uint(h),
                                   __ATOMIC_RELAXED, __HIP_MEMORY_SCOPE_AGENT);
                // bf16 packed y0 (read only by next kernel -> plain store)
                const float hp = __shfl_xor(h, 1);
                if ((ej & 1) == 0) {
                    const unsigned int pk = (unsigned int)f2b(h)
                                          | ((unsigned int)f2b(hp) << 16);
                    *((unsigned int*)yout_ + (size_t)eb * SS * HH + (size_t)t * HH
                                           + dir * (HH / 2) + ((jbase + ej) >> 1)) = pk;
                }
            } else {
                const size_t idx = ((size_t)eb * SS + t) * (2 * HH) + dir * HH + jbase + ej;
                __hip_atomic_store((unsigned int*)yout_ + idx, __float_as_uint(h),
                                   __ATOMIC_RELAXED, __HIP_MEMORY_SCOPE_AGENT);
                if (st == SS - 1) {
                    hn[(dir * BB + eb) * HH + jbase + ej] = h;
                    cn[(dir * BB + eb) * HH + jbase + ej] = creg;
                }
            }
        }

        // ---- publish h_t ----
        __builtin_amdgcn_fence(__ATOMIC_RELEASE, "agent");
        __syncthreads();
        if (tid == 0)
            __hip_atomic_fetch_add(&cbase[st], 1u, __ATOMIC_RELEASE,
                                   __HIP_MEMORY_SCOPE_AGENT);
    }
}

extern "C" void kernel_launch(void* const* d_in, const int* in_sizes, int n_in,
                              void* d_out, int out_size, void* d_ws, size_t ws_size,
                              hipStream_t stream) {
    (void)in_sizes; (void)n_in;

    const float* x      = (const float*)d_in[0];
    const float* Wih_f0 = (const float*)d_in[1];
    const float* Whh_f0 = (const float*)d_in[2];
    const float* b_f0   = (const float*)d_in[3];
    const float* Wih_b0 = (const float*)d_in[4];
    const float* Whh_b0 = (const float*)d_in[5];
    const float* b_b0   = (const float*)d_in[6];
    const float* Wih_f1 = (const float*)d_in[7];
    const float* Whh_f1 = (const float*)d_in[8];
    const float* b_f1   = (const float*)d_in[9];
    const float* Wih_b1 = (const float*)d_in[10];
    const float* Whh_b1 = (const float*)d_in[11];
    const float* b_b1   = (const float*)d_in[12];

    // ws: [0,32Mi) y0 bf16 [B,S,2H]; +8K ctr0[2S]; +8K ctr1[2S]; +512K hrec f32
    char* ws = (char*)d_ws;
    const size_t Y0B  = (size_t)BB * SS * 2 * HH * 2;             // 33,554,432
    const size_t HREC = (size_t)2 * 2 * BB * HH * 4;              // 524,288
    const size_t NEED = Y0B + 16384 + HREC;
    if (ws_size < NEED) return;
    if ((size_t)out_size < (size_t)BB * SS * 2 * HH + 4 * BB * HH) return;

    unsigned short* y0   = (unsigned short*)(ws);
    unsigned int*   ctr0 = (unsigned int*)(ws + Y0B);             // [2][512]
    unsigned int*   ctr1 = (unsigned int*)(ws + Y0B + 8192);      // [2][512]
    float*          hrec = (float*)(ws + Y0B + 16384);

    float* out = (float*)d_out;                          // [B,S,2H] f32
    float* hn  = out + (size_t)BB * SS * 2 * HH;         // [2,B,H]
    float* cn  = hn + 2 * BB * HH;                       // [2,B,H]

    hipMemsetAsync(ws + Y0B, 0, 16384, stream);          // zero barrier counters

    constexpr int SMB = 2 * WR * WST * 2 + 32 * 36 * 4 + 128;   // 71,296 B
    hipFuncSetAttribute(reinterpret_cast<const void*>(lstm_layer<512,  true>),
                        hipFuncAttributeMaxDynamicSharedMemorySize, SMB);
    hipFuncSetAttribute(reinterpret_cast<const void*>(lstm_layer<1024, false>),
                        hipFuncAttributeMaxDynamicSharedMemorySize, SMB);

    lstm_layer<512, true><<<128, 256, SMB, stream>>>(
        x, Wih_f0, Whh_f0, b_f0, Wih_b0, Whh_b0, b_b0,
        (void*)y0, hrec, ctr0, nullptr, nullptr);

    lstm_layer<1024, false><<<128, 256, SMB, stream>>>(
        y0, Wih_f1, Whh_f1, b_f1, Wih_b1, Whh_b1, b_b1,
        (void*)out, nullptr, ctr1, hn, cn);
}

// Round 8
// 14344.232 us; speedup vs baseline: 2.1916x; 2.1916x over previous
//
#include <hip/hip_runtime.h>
#include <cstdint>
#include <cstddef>

#define BB 32
#define SS 512
#define HH 512
#define NBD 64      // blocks per direction
#define JPB 8       // j columns per block
#define WR 32       // W rows per block (4 gates * JPB)
#define WST 520     // Whh LDS row stride

typedef short v8s __attribute__((ext_vector_type(8)));
typedef float v4f __attribute__((ext_vector_type(4)));
typedef unsigned long long u64t;

static __device__ __forceinline__ float b2f(unsigned short u) {
    union { unsigned int i; float f; } v; v.i = ((unsigned int)u) << 16; return v.f;
}
static __device__ __forceinline__ unsigned short f2b(float f) {
    union { float f; unsigned int i; } v; v.f = f;
    unsigned int u = v.i;
    return (unsigned short)((u + 0x7fffu + ((u >> 16) & 1u)) >> 16);  // RNE
}
static __device__ __forceinline__ void split1(float f, short& hi, short& lo) {
    const unsigned short h = f2b(f);
    hi = (short)h;
    lo = (short)f2b(f - b2f(h));   // exact residual, then RNE
}
static __device__ __forceinline__ void split8(const float* __restrict__ p, v8s& hi, v8s& lo) {
    #pragma unroll
    for (int e = 0; e < 8; ++e) { short h, l; split1(p[e], h, l); hi[e] = h; lo[e] = l; }
}

#define MFMA(a, b, c) __builtin_amdgcn_mfma_f32_16x16x32_bf16((a), (b), (c), 0, 0, 0)

// One bidirectional layer; persistent blocks, per-timestep producer flags.
// blockIdx: [0,64) forward, [64,128) backward j-blocks.
// Sync design (r8): NO agent fences anywhere (they L2-invalidated x/W every
// step -> 532MB FETCH + us-scale stalls). h-exchange via 8B relaxed agent
// atomics (coherent point, no caching to invalidate). Arrival: s_waitcnt(0)
// + barrier + per-block flag slot (no contention). Wait: lanes 0..63 poll
// their own slot. Numerics identical to r7 (split-bf16, f32 h-exchange).
template<int DIN, bool L0>
__global__ __launch_bounds__(256, 1)
void lstm_layer(const void*  __restrict__ xin_,
                const float* __restrict__ Wih_f,  // [4H, DIN] f32
                const float* __restrict__ Whh_f,  // [4H, H]  f32
                const float* __restrict__ b_f,    // [4H]     f32
                const float* __restrict__ Wih_b,
                const float* __restrict__ Whh_b,
                const float* __restrict__ b_b,
                void*  __restrict__ yout_,         // L0: bf16 [B,S,2H]; L1: f32 [B,S,2H]
                float* __restrict__ hrec,          // [2dir][2par][B][H] f32 exchange
                unsigned int* __restrict__ flags,  // [2dir][S][64], zeroed each call
                float* __restrict__ hn,            // [2][B][H] f32 (L1) or nullptr
                float* __restrict__ cn)            // [2][B][H] f32 (L1) or nullptr
{
    constexpr int NKX = DIN / 32;
    constexpr int NKH = HH / 32;

    extern __shared__ char smem[];
    unsigned short* WhhHi = (unsigned short*)smem;          // [32][WST]
    unsigned short* WhhLo = WhhHi + WR * WST;               // [32][WST]
    float* gatesl = (float*)(smem + 2 * WR * WST * 2);      // [32][36]
    float* biasl  = gatesl + 32 * 36;

    const int tid   = threadIdx.x;
    const int dir   = blockIdx.x >> 6;
    const int jb    = blockIdx.x & 63;
    const int jbase = jb * JPB;

    const float* Wih = dir ? Wih_b : Wih_f;
    const float* Whh = dir ? Whh_b : Whh_f;
    const float* bv  = dir ? b_b  : b_f;

    // ---- stage Whh slice split hi/lo into LDS ----
    {
        const int r  = tid >> 3;
        const int c0 = (tid & 7) * 64;
        const int R  = (r >> 3) * HH + jbase + (r & 7);   // gate*512 + j
        const float* src = Whh + (size_t)R * HH + c0;
        #pragma unroll
        for (int c = 0; c < 64; c += 8) {
            v8s hi, lo; split8(src + c, hi, lo);
            *(v8s*)(WhhHi + r * WST + c0 + c) = hi;
            *(v8s*)(WhhLo + r * WST + c0 + c) = lo;
        }
    }
    if (tid < WR) biasl[tid] = bv[(tid >> 3) * HH + jbase + (tid & 7)];

    const int lane = tid & 63;
    const int wv   = tid >> 6;
    const int mi   = wv & 1;         // M-frag (batch half)
    const int ni   = wv >> 1;        // N-frag (gate-row half)
    const int g    = lane >> 4;      // k-group
    const int rA   = lane & 15;

    const int brow = mi * 16 + rA;   // batch row (A-frag)
    const int nrow = ni * 16 + rA;   // local gate-row (B-frag)
    const int Rn   = (nrow >> 3) * HH + jbase + (nrow & 7);

    // ---- Wih B-fragments split hi/lo into registers (static indexing) ----
    v8s wxh[NKX], wxl[NKX];
    {
        const float* src = Wih + (size_t)Rn * DIN + 8 * g;
        #pragma unroll
        for (int kt = 0; kt < NKX; ++kt) split8(src + kt * 32, wxh[kt], wxl[kt]);
    }
    __syncthreads();

    const float*          aXf = L0 ? (const float*)xin_ + (size_t)brow * SS * DIN + 8 * g : nullptr;
    const unsigned short* aXb = L0 ? nullptr : (const unsigned short*)xin_ + (size_t)brow * SS * DIN + 8 * g;
    const unsigned short* bHb = WhhHi + nrow * WST + 8 * g;
    const unsigned short* bLb = WhhLo + nrow * WST + 8 * g;

    unsigned int* fbase = flags + (size_t)dir * SS * 64;   // per-direction flag plane

    const int eb = tid >> 3;         // epilogue: batch row
    const int ej = tid & 7;          // epilogue: local col
    float creg = 0.f;

    for (int st = 0; st < SS; ++st) {
        const int t = dir ? (SS - 1 - st) : st;

        v4f acc0 = {0,0,0,0}, acc1 = {0,0,0,0}, acc2 = {0,0,0,0};
        v4f acc3 = {0,0,0,0}, acc4 = {0,0,0,0}, acc5 = {0,0,0,0};

        // ---- x-part (pre-barrier; hidden under peers' publish latency) ----
        if (L0) {
            const float* aX = aXf + (size_t)t * DIN;
            #pragma unroll
            for (int kt = 0; kt < NKX; kt += 2) {
                v8s ah0, al0, ah1, al1;
                split8(aX + kt * 32, ah0, al0);
                split8(aX + (kt + 1) * 32, ah1, al1);
                acc0 = MFMA(ah0, wxh[kt],     acc0);
                acc1 = MFMA(ah1, wxh[kt + 1], acc1);
                acc2 = MFMA(ah0, wxl[kt],     acc2);
                acc3 = MFMA(ah1, wxl[kt + 1], acc3);
                acc4 = MFMA(al0, wxh[kt],     acc4);
                acc5 = MFMA(al1, wxh[kt + 1], acc5);
            }
        } else {
            const unsigned short* aX = aXb + (size_t)t * DIN;
            #pragma unroll
            for (int kt = 0; kt < NKX; kt += 2) {
                v8s a0 = *(const v8s*)(aX + kt * 32);
                v8s a1 = *(const v8s*)(aX + (kt + 1) * 32);
                acc0 = MFMA(a0, wxh[kt],     acc0);
                acc1 = MFMA(a1, wxh[kt + 1], acc1);
                acc2 = MFMA(a0, wxl[kt],     acc2);
                acc3 = MFMA(a1, wxl[kt + 1], acc3);
            }
        }

        // ---- wait for h_{t_prev}: each lane polls one producer's flag ----
        if (st > 0) {
            if (tid < 64) {
                const unsigned int* f = fbase + (size_t)(st - 1) * 64 + tid;
                int guard = 0;
                while (!__hip_atomic_load(f, __ATOMIC_RELAXED,
                                          __HIP_MEMORY_SCOPE_AGENT)) {
                    __builtin_amdgcn_s_sleep(1);
                    if (++guard > (1 << 26)) break;   // anti-hang escape
                }
            }
            __syncthreads();
            // no fence: h data travels via coherent-point atomics below

            const u64t* hb = (const u64t*)hrec
                + (((size_t)(dir * 2 + ((st - 1) & 1))) * BB * HH + brow * HH + 8 * g) / 2;
            #pragma unroll
            for (int kt = 0; kt < NKH; kt += 2) {
                u64t q0[4], q1[4];
                #pragma unroll
                for (int ii = 0; ii < 4; ++ii) {
                    q0[ii] = __hip_atomic_load(hb + kt * 16 + ii,
                                 __ATOMIC_RELAXED, __HIP_MEMORY_SCOPE_AGENT);
                    q1[ii] = __hip_atomic_load(hb + (kt + 1) * 16 + ii,
                                 __ATOMIC_RELAXED, __HIP_MEMORY_SCOPE_AGENT);
                }
                v8s ah0, al0, ah1, al1;
                #pragma unroll
                for (int ii = 0; ii < 4; ++ii) {
                    short h, l;
                    split1(__uint_as_float((unsigned int)(q0[ii] & 0xffffffffu)), h, l);
                    ah0[2 * ii] = h; al0[2 * ii] = l;
                    split1(__uint_as_float((unsigned int)(q0[ii] >> 32)), h, l);
                    ah0[2 * ii + 1] = h; al0[2 * ii + 1] = l;
                    split1(__uint_as_float((unsigned int)(q1[ii] & 0xffffffffu)), h, l);
                    ah1[2 * ii] = h; al1[2 * ii] = l;
                    split1(__uint_as_float((unsigned int)(q1[ii] >> 32)), h, l);
                    ah1[2 * ii + 1] = h; al1[2 * ii + 1] = l;
                }
                v8s bh0 = *(const v8s*)(bHb + kt * 32);
                v8s bl0 = *(const v8s*)(bLb + kt * 32);
                v8s bh1 = *(const v8s*)(bHb + (kt + 1) * 32);
                v8s bl1 = *(const v8s*)(bLb + (kt + 1) * 32);
                acc0 = MFMA(ah0, bh0, acc0);
                acc1 = MFMA(ah1, bh1, acc1);
                acc2 = MFMA(ah0, bl0, acc2);
                acc3 = MFMA(ah1, bl1, acc3);
                acc4 = MFMA(al0, bh0, acc4);
                acc5 = MFMA(al1, bh1, acc5);
            }
        }
        acc0 = ((acc0 + acc1) + (acc2 + acc3)) + (acc4 + acc5);

        // ---- exchange gate preacts via LDS (C/D m89, probe-confirmed r4) ----
        {
            const int gb = mi * 16 + 4 * g;
            const int gw = ni * 16 + rA;
            gatesl[(gb + 0) * 36 + gw] = acc0[0];
            gatesl[(gb + 1) * 36 + gw] = acc0[1];
            gatesl[(gb + 2) * 36 + gw] = acc0[2];
            gatesl[(gb + 3) * 36 + gw] = acc0[3];
        }
        __syncthreads();

        // ---- gates (torch order i,f,g,o) + state update ----
        {
            const float pi = gatesl[eb * 36 +      ej] + biasl[     ej];
            const float pf = gatesl[eb * 36 +  8 + ej] + biasl[ 8 + ej];
            const float pg = gatesl[eb * 36 + 16 + ej] + biasl[16 + ej];
            const float po = gatesl[eb * 36 + 24 + ej] + biasl[24 + ej];
            const float ig = 1.f / (1.f + __expf(-pi));
            const float fg = 1.f / (1.f + __expf(-pf));
            const float gg = tanhf(pg);
            const float og = 1.f / (1.f + __expf(-po));
            creg = fg * creg + ig * gg;
            const float h = og * tanhf(creg);

            // h-exchange: packed 2xf32 relaxed agent atomic into hrec parity buf
            const float hp = __shfl_xor(h, 1);
            if ((ej & 1) == 0) {
                const u64t pk = ((u64t)__float_as_uint(hp) << 32)
                              | (u64t)__float_as_uint(h);
                u64t* hw = (u64t*)(hrec
                         + ((size_t)(dir * 2 + (st & 1))) * BB * HH + eb * HH + jbase + ej);
                __hip_atomic_store(hw, pk, __ATOMIC_RELAXED, __HIP_MEMORY_SCOPE_AGENT);
            }

            // y output: plain cached stores (consumed only after kernel boundary)
            if (L0) {
                if ((ej & 1) == 0) {
                    const unsigned int pk = (unsigned int)f2b(h)
                                          | ((unsigned int)f2b(hp) << 16);
                    *((unsigned int*)yout_ + (size_t)eb * SS * HH + (size_t)t * HH
                                           + dir * (HH / 2) + ((jbase + ej) >> 1)) = pk;
                }
            } else {
                ((float*)yout_)[((size_t)eb * SS + t) * (2 * HH) + dir * HH + jbase + ej] = h;
                if (st == SS - 1) {
                    hn[(dir * BB + eb) * HH + jbase + ej] = h;
                    cn[(dir * BB + eb) * HH + jbase + ej] = creg;
                }
            }
        }

        // ---- publish: drain my stores, block-barrier, set my flag slot ----
        __builtin_amdgcn_s_waitcnt(0);
        __syncthreads();
        if (tid == 0)
            __hip_atomic_store(fbase + (size_t)st * 64 + jb, 1u,
                               __ATOMIC_RELAXED, __HIP_MEMORY_SCOPE_AGENT);
    }
}

extern "C" void kernel_launch(void* const* d_in, const int* in_sizes, int n_in,
                              void* d_out, int out_size, void* d_ws, size_t ws_size,
                              hipStream_t stream) {
    (void)in_sizes; (void)n_in;

    const float* x      = (const float*)d_in[0];
    const float* Wih_f0 = (const float*)d_in[1];
    const float* Whh_f0 = (const float*)d_in[2];
    const float* b_f0   = (const float*)d_in[3];
    const float* Wih_b0 = (const float*)d_in[4];
    const float* Whh_b0 = (const float*)d_in[5];
    const float* b_b0   = (const float*)d_in[6];
    const float* Wih_f1 = (const float*)d_in[7];
    const float* Whh_f1 = (const float*)d_in[8];
    const float* b_f1   = (const float*)d_in[9];
    const float* Wih_b1 = (const float*)d_in[10];
    const float* Whh_b1 = (const float*)d_in[11];
    const float* b_b1   = (const float*)d_in[12];

    // ws: [0,32Mi) y0 bf16; +256K flags0[2][512][64]; +256K flags1; +512K hrec f32
    char* ws = (char*)d_ws;
    const size_t Y0B  = (size_t)BB * SS * 2 * HH * 2;             // 33,554,432
    const size_t FLG  = (size_t)2 * SS * 64 * 4;                  // 262,144 each
    const size_t HREC = (size_t)2 * 2 * BB * HH * 4;              // 524,288
    const size_t NEED = Y0B + 2 * FLG + HREC;
    if (ws_size < NEED) return;
    if ((size_t)out_size < (size_t)BB * SS * 2 * HH + 4 * BB * HH) return;

    unsigned short* y0     = (unsigned short*)(ws);
    unsigned int*   flags0 = (unsigned int*)(ws + Y0B);
    unsigned int*   flags1 = (unsigned int*)(ws + Y0B + FLG);
    float*          hrec   = (float*)(ws + Y0B + 2 * FLG);        // shared (sequential kernels)

    float* out = (float*)d_out;                          // [B,S,2H] f32
    float* hn  = out + (size_t)BB * SS * 2 * HH;         // [2,B,H]
    float* cn  = hn + 2 * BB * HH;                       // [2,B,H]

    hipMemsetAsync(ws + Y0B, 0, 2 * FLG, stream);        // zero flags each call

    constexpr int SMB = 2 * WR * WST * 2 + 32 * 36 * 4 + 128;   // 71,296 B
    hipFuncSetAttribute(reinterpret_cast<const void*>(lstm_layer<512,  true>),
                        hipFuncAttributeMaxDynamicSharedMemorySize, SMB);
    hipFuncSetAttribute(reinterpret_cast<const void*>(lstm_layer<1024, false>),
                        hipFuncAttributeMaxDynamicSharedMemorySize, SMB);

    lstm_layer<512, true><<<128, 256, SMB, stream>>>(
        x, Wih_f0, Whh_f0, b_f0, Wih_b0, Whh_b0, b_b0,
        (void*)y0, hrec, flags0, nullptr, nullptr);

    lstm_layer<1024, false><<<128, 256, SMB, stream>>>(
        y0, Wih_f1, Whh_f1, b_f1, Wih_b1, Whh_b1, b_b1,
        (void*)out, hrec, flags1, hn, cn);
}

// Round 9
// 9904.286 us; speedup vs baseline: 3.1740x; 1.4483x over previous
//
#include <hip/hip_runtime.h>
#include <cstdint>
#include <cstddef>

#define BB 32
#define SS 512
#define HH 512
#define NBD 64      // blocks per direction
#define JPB 8       // j columns per block
#define WR 32       // W rows per block (4 gates * JPB)
#define WST 520     // Whh LDS row stride (bf16 elems)
#define HST 520     // h LDS row stride (bf16 elems)

typedef short v8s __attribute__((ext_vector_type(8)));
typedef float v4f __attribute__((ext_vector_type(4)));
typedef unsigned long long u64t;

static __device__ __forceinline__ float b2f(unsigned short u) {
    union { unsigned int i; float f; } v; v.i = ((unsigned int)u) << 16; return v.f;
}
static __device__ __forceinline__ unsigned short f2b(float f) {
    union { float f; unsigned int i; } v; v.f = f;
    unsigned int u = v.i;
    return (unsigned short)((u + 0x7fffu + ((u >> 16) & 1u)) >> 16);  // RNE
}
static __device__ __forceinline__ void split1(float f, short& hi, short& lo) {
    const unsigned short h = f2b(f);
    hi = (short)h;
    lo = (short)f2b(f - b2f(h));   // exact residual, then RNE
}
static __device__ __forceinline__ void split8(const float* __restrict__ p, v8s& hi, v8s& lo) {
    #pragma unroll
    for (int e = 0; e < 8; ++e) { short h, l; split1(p[e], h, l); hi[e] = h; lo[e] = l; }
}

#define MFMA(a, b, c) __builtin_amdgcn_mfma_f32_16x16x32_bf16((a), (b), (c), 0, 0, 0)

// One bidirectional layer; persistent blocks, per-timestep producer flags.
// r9: (1) cooperative h staging — 256 threads batch-load the unique 64KB h
// slice as 32 independent coalesced u64 relaxed-atomic loads each (fully
// pipelined, ~1 coherent-point round trip), split hi/lo ONCE, stage in padded
// LDS planes; fragments then come from ds_read_b128 with no per-use VALU.
// (2) publish reorder — only hrec stores are drained before the flag; y/hn/cn
// stores issue after the flag and drain under the next step's x-part.
// Numerics identical to r7/r8 (split-bf16 everywhere, f32 h-exchange).
template<int DIN, bool L0>
__global__ __launch_bounds__(256, 1)
void lstm_layer(const void*  __restrict__ xin_,
                const float* __restrict__ Wih_f,  // [4H, DIN] f32
                const float* __restrict__ Whh_f,  // [4H, H]  f32
                const float* __restrict__ b_f,    // [4H]     f32
                const float* __restrict__ Wih_b,
                const float* __restrict__ Whh_b,
                const float* __restrict__ b_b,
                void*  __restrict__ yout_,         // L0: bf16 [B,S,2H]; L1: f32 [B,S,2H]
                float* __restrict__ hrec,          // [2dir][2par][B][H] f32 exchange
                unsigned int* __restrict__ flags,  // [2dir][S][64], zeroed each call
                float* __restrict__ hn,            // [2][B][H] f32 (L1) or nullptr
                float* __restrict__ cn)            // [2][B][H] f32 (L1) or nullptr
{
    constexpr int NKX = DIN / 32;
    constexpr int NKH = HH / 32;

    extern __shared__ char smem[];
    unsigned short* WhhHi = (unsigned short*)smem;          // [32][WST]
    unsigned short* WhhLo = WhhHi + WR * WST;               // [32][WST]
    unsigned short* hHi   = WhhLo + WR * WST;               // [32][HST] batch-major
    unsigned short* hLo   = hHi + BB * HST;                 // [32][HST]
    float* gatesl = (float*)(hLo + BB * HST);               // [32][36]
    float* biasl  = gatesl + 32 * 36;

    const int tid   = threadIdx.x;
    const int dir   = blockIdx.x >> 6;
    const int jb    = blockIdx.x & 63;
    const int jbase = jb * JPB;

    const float* Wih = dir ? Wih_b : Wih_f;
    const float* Whh = dir ? Whh_b : Whh_f;
    const float* bv  = dir ? b_b  : b_f;

    // ---- stage Whh slice split hi/lo into LDS ----
    {
        const int r  = tid >> 3;
        const int c0 = (tid & 7) * 64;
        const int R  = (r >> 3) * HH + jbase + (r & 7);   // gate*512 + j
        const float* src = Whh + (size_t)R * HH + c0;
        #pragma unroll
        for (int c = 0; c < 64; c += 8) {
            v8s hi, lo; split8(src + c, hi, lo);
            *(v8s*)(WhhHi + r * WST + c0 + c) = hi;
            *(v8s*)(WhhLo + r * WST + c0 + c) = lo;
        }
    }
    if (tid < WR) biasl[tid] = bv[(tid >> 3) * HH + jbase + (tid & 7)];

    const int lane = tid & 63;
    const int wv   = tid >> 6;
    const int mi   = wv & 1;         // M-frag (batch half)
    const int ni   = wv >> 1;        // N-frag (gate-row half)
    const int g    = lane >> 4;      // k-group
    const int rA   = lane & 15;

    const int brow = mi * 16 + rA;   // batch row (A-frag)
    const int nrow = ni * 16 + rA;   // local gate-row (B-frag)
    const int Rn   = (nrow >> 3) * HH + jbase + (nrow & 7);

    // ---- Wih B-fragments split hi/lo into registers (static indexing) ----
    v8s wxh[NKX], wxl[NKX];
    {
        const float* src = Wih + (size_t)Rn * DIN + 8 * g;
        #pragma unroll
        for (int kt = 0; kt < NKX; ++kt) split8(src + kt * 32, wxh[kt], wxl[kt]);
    }
    __syncthreads();

    const float*          aXf = L0 ? (const float*)xin_ + (size_t)brow * SS * DIN + 8 * g : nullptr;
    const unsigned short* aXb = L0 ? nullptr : (const unsigned short*)xin_ + (size_t)brow * SS * DIN + 8 * g;
    const unsigned short* bHb = WhhHi + nrow * WST + 8 * g;
    const unsigned short* bLb = WhhLo + nrow * WST + 8 * g;

    unsigned int* fbase = flags + (size_t)dir * SS * 64;   // per-direction flag plane

    const int eb = tid >> 3;         // epilogue: batch row
    const int ej = tid & 7;          // epilogue: local col
    float creg = 0.f;

    for (int st = 0; st < SS; ++st) {
        const int t = dir ? (SS - 1 - st) : st;

        v4f acc0 = {0,0,0,0}, acc1 = {0,0,0,0}, acc2 = {0,0,0,0};
        v4f acc3 = {0,0,0,0}, acc4 = {0,0,0,0}, acc5 = {0,0,0,0};

        // ---- x-part (pre-wait; overlaps peers' publish latency) ----
        if (L0) {
            const float* aX = aXf + (size_t)t * DIN;
            #pragma unroll
            for (int kt = 0; kt < NKX; kt += 2) {
                v8s ah0, al0, ah1, al1;
                split8(aX + kt * 32, ah0, al0);
                split8(aX + (kt + 1) * 32, ah1, al1);
                acc0 = MFMA(ah0, wxh[kt],     acc0);
                acc1 = MFMA(ah1, wxh[kt + 1], acc1);
                acc2 = MFMA(ah0, wxl[kt],     acc2);
                acc3 = MFMA(ah1, wxl[kt + 1], acc3);
                acc4 = MFMA(al0, wxh[kt],     acc4);
                acc5 = MFMA(al1, wxh[kt + 1], acc5);
            }
        } else {
            const unsigned short* aX = aXb + (size_t)t * DIN;
            #pragma unroll
            for (int kt = 0; kt < NKX; kt += 2) {
                v8s a0 = *(const v8s*)(aX + kt * 32);
                v8s a1 = *(const v8s*)(aX + (kt + 1) * 32);
                acc0 = MFMA(a0, wxh[kt],     acc0);
                acc1 = MFMA(a1, wxh[kt + 1], acc1);
                acc2 = MFMA(a0, wxl[kt],     acc2);
                acc3 = MFMA(a1, wxl[kt + 1], acc3);
            }
        }

        // ---- wait for h_{t_prev}; cooperative stage; h-part ----
        if (st > 0) {
            if (tid < 64) {
                const unsigned int* f = fbase + (size_t)(st - 1) * 64 + tid;
                int guard = 0;
                while (!__hip_atomic_load(f, __ATOMIC_RELAXED,
                                          __HIP_MEMORY_SCOPE_AGENT)) {
                    __builtin_amdgcn_s_sleep(1);
                    if (++guard > (1 << 26)) break;   // anti-hang escape
                }
            }
            __syncthreads();   // all threads past poll; previous h LDS reads done

            // cooperative batched load of the unique [32][512] f32 h slice:
            // thread loads u64 k*256+tid -> row k, cols 2*tid, 2*tid+1
            const u64t* hsrc = (const u64t*)hrec
                + ((size_t)(dir * 2 + ((st - 1) & 1)) * BB * HH) / 2;
            u64t vals[32];
            #pragma unroll
            for (int k = 0; k < 32; ++k)
                vals[k] = __hip_atomic_load(hsrc + (size_t)k * 256 + tid,
                                            __ATOMIC_RELAXED, __HIP_MEMORY_SCOPE_AGENT);
            #pragma unroll
            for (int k = 0; k < 32; ++k) {
                const float f0 = __uint_as_float((unsigned int)(vals[k] & 0xffffffffu));
                const float f1 = __uint_as_float((unsigned int)(vals[k] >> 32));
                short h0, l0, h1, l1;
                split1(f0, h0, l0);
                split1(f1, h1, l1);
                *(unsigned int*)(hHi + k * HST + 2 * tid) =
                    (unsigned int)(unsigned short)h0 | ((unsigned int)(unsigned short)h1 << 16);
                *(unsigned int*)(hLo + k * HST + 2 * tid) =
                    (unsigned int)(unsigned short)l0 | ((unsigned int)(unsigned short)l1 << 16);
            }
            __syncthreads();

            const unsigned short* aHh = hHi + brow * HST + 8 * g;
            const unsigned short* aHl = hLo + brow * HST + 8 * g;
            #pragma unroll
            for (int kt = 0; kt < NKH; kt += 2) {
                v8s ah0 = *(const v8s*)(aHh + kt * 32);
                v8s al0 = *(const v8s*)(aHl + kt * 32);
                v8s ah1 = *(const v8s*)(aHh + (kt + 1) * 32);
                v8s al1 = *(const v8s*)(aHl + (kt + 1) * 32);
                v8s bh0 = *(const v8s*)(bHb + kt * 32);
                v8s bl0 = *(const v8s*)(bLb + kt * 32);
                v8s bh1 = *(const v8s*)(bHb + (kt + 1) * 32);
                v8s bl1 = *(const v8s*)(bLb + (kt + 1) * 32);
                acc0 = MFMA(ah0, bh0, acc0);
                acc1 = MFMA(ah1, bh1, acc1);
                acc2 = MFMA(ah0, bl0, acc2);
                acc3 = MFMA(ah1, bl1, acc3);
                acc4 = MFMA(al0, bh0, acc4);
                acc5 = MFMA(al1, bh1, acc5);
            }
        }
        acc0 = ((acc0 + acc1) + (acc2 + acc3)) + (acc4 + acc5);

        // ---- exchange gate preacts via LDS (C/D m89, probe-confirmed r4) ----
        {
            const int gb = mi * 16 + 4 * g;
            const int gw = ni * 16 + rA;
            gatesl[(gb + 0) * 36 + gw] = acc0[0];
            gatesl[(gb + 1) * 36 + gw] = acc0[1];
            gatesl[(gb + 2) * 36 + gw] = acc0[2];
            gatesl[(gb + 3) * 36 + gw] = acc0[3];
        }
        __syncthreads();

        // ---- gates (torch order i,f,g,o) + state update + publish ----
        {
            const float pi = gatesl[eb * 36 +      ej] + biasl[     ej];
            const float pf = gatesl[eb * 36 +  8 + ej] + biasl[ 8 + ej];
            const float pg = gatesl[eb * 36 + 16 + ej] + biasl[16 + ej];
            const float po = gatesl[eb * 36 + 24 + ej] + biasl[24 + ej];
            const float ig = 1.f / (1.f + __expf(-pi));
            const float fg = 1.f / (1.f + __expf(-pf));
            const float gg = tanhf(pg);
            const float og = 1.f / (1.f + __expf(-po));
            creg = fg * creg + ig * gg;
            const float h = og * tanhf(creg);
            const float hp = __shfl_xor(h, 1);

            // 1) h-exchange store (the only store on the inter-block path)
            if ((ej & 1) == 0) {
                const u64t pk = ((u64t)__float_as_uint(hp) << 32)
                              | (u64t)__float_as_uint(h);
                u64t* hw = (u64t*)(hrec
                         + ((size_t)(dir * 2 + (st & 1))) * BB * HH + eb * HH + jbase + ej);
                __hip_atomic_store(hw, pk, __ATOMIC_RELAXED, __HIP_MEMORY_SCOPE_AGENT);
            }
            // 2) drain vmem (h store), 3) block barrier, 4) flag
            asm volatile("s_waitcnt vmcnt(0)" ::: "memory");
            __syncthreads();
            if (tid == 0)
                __hip_atomic_store(fbase + (size_t)st * 64 + jb, 1u,
                                   __ATOMIC_RELAXED, __HIP_MEMORY_SCOPE_AGENT);

            // 5) y output stores AFTER the flag (drain under next step's x-part)
            if (L0) {
                if ((ej & 1) == 0) {
                    const unsigned int pk = (unsigned int)f2b(h)
                                          | ((unsigned int)f2b(hp) << 16);
                    *((unsigned int*)yout_ + (size_t)eb * SS * HH + (size_t)t * HH
                                           + dir * (HH / 2) + ((jbase + ej) >> 1)) = pk;
                }
            } else {
                ((float*)yout_)[((size_t)eb * SS + t) * (2 * HH) + dir * HH + jbase + ej] = h;
                if (st == SS - 1) {
                    hn[(dir * BB + eb) * HH + jbase + ej] = h;
                    cn[(dir * BB + eb) * HH + jbase + ej] = creg;
                }
            }
        }
    }
}

extern "C" void kernel_launch(void* const* d_in, const int* in_sizes, int n_in,
                              void* d_out, int out_size, void* d_ws, size_t ws_size,
                              hipStream_t stream) {
    (void)in_sizes; (void)n_in;

    const float* x      = (const float*)d_in[0];
    const float* Wih_f0 = (const float*)d_in[1];
    const float* Whh_f0 = (const float*)d_in[2];
    const float* b_f0   = (const float*)d_in[3];
    const float* Wih_b0 = (const float*)d_in[4];
    const float* Whh_b0 = (const float*)d_in[5];
    const float* b_b0   = (const float*)d_in[6];
    const float* Wih_f1 = (const float*)d_in[7];
    const float* Whh_f1 = (const float*)d_in[8];
    const float* b_f1   = (const float*)d_in[9];
    const float* Wih_b1 = (const float*)d_in[10];
    const float* Whh_b1 = (const float*)d_in[11];
    const float* b_b1   = (const float*)d_in[12];

    // ws: [0,32Mi) y0 bf16; +256K flags0[2][512][64]; +256K flags1; +512K hrec f32
    char* ws = (char*)d_ws;
    const size_t Y0B  = (size_t)BB * SS * 2 * HH * 2;             // 33,554,432
    const size_t FLG  = (size_t)2 * SS * 64 * 4;                  // 262,144 each
    const size_t HREC = (size_t)2 * 2 * BB * HH * 4;              // 524,288
    const size_t NEED = Y0B + 2 * FLG + HREC;
    if (ws_size < NEED) return;
    if ((size_t)out_size < (size_t)BB * SS * 2 * HH + 4 * BB * HH) return;

    unsigned short* y0     = (unsigned short*)(ws);
    unsigned int*   flags0 = (unsigned int*)(ws + Y0B);
    unsigned int*   flags1 = (unsigned int*)(ws + Y0B + FLG);
    float*          hrec   = (float*)(ws + Y0B + 2 * FLG);        // shared (sequential kernels)

    float* out = (float*)d_out;                          // [B,S,2H] f32
    float* hn  = out + (size_t)BB * SS * 2 * HH;         // [2,B,H]
    float* cn  = hn + 2 * BB * HH;                       // [2,B,H]

    hipMemsetAsync(ws + Y0B, 0, 2 * FLG, stream);        // zero flags each call

    // LDS: Whh hi/lo (66,560) + h hi/lo (66,560) + gates (4,608) + bias (128)
    constexpr int SMB = 2 * WR * WST * 2 + 2 * BB * HST * 2 + 32 * 36 * 4 + 128;  // 137,984
    hipFuncSetAttribute(reinterpret_cast<const void*>(lstm_layer<512,  true>),
                        hipFuncAttributeMaxDynamicSharedMemorySize, SMB);
    hipFuncSetAttribute(reinterpret_cast<const void*>(lstm_layer<1024, false>),
                        hipFuncAttributeMaxDynamicSharedMemorySize, SMB);

    lstm_layer<512, true><<<128, 256, SMB, stream>>>(
        x, Wih_f0, Whh_f0, b_f0, Wih_b0, Whh_b0, b_b0,
        (void*)y0, hrec, flags0, nullptr, nullptr);

    lstm_layer<1024, false><<<128, 256, SMB, stream>>>(
        y0, Wih_f1, Whh_f1, b_f1, Wih_b1, Whh_b1, b_b1,
        (void*)out, hrec, flags1, hn, cn);
}